// Round 10
// baseline (246.326 us; speedup 1.0000x reference)
//
#include <hip/hip_runtime.h>
#include <stdint.h>

typedef __bf16 bf16x8 __attribute__((ext_vector_type(8)));
typedef float floatx4 __attribute__((ext_vector_type(4)));
typedef unsigned short u16;
typedef u16 u16x8 __attribute__((ext_vector_type(8)));

__device__ __forceinline__ float bf2f(u16 u) {
    union { uint32_t i; float f; } v; v.i = ((uint32_t)u) << 16; return v.f;
}
__device__ __forceinline__ u16 f2bf(float f) {
    union { float f; uint32_t i; } v; v.f = f;
    uint32_t r = v.i + 0x7fffu + ((v.i >> 16) & 1u);
    return (u16)(r >> 16);
}

// async global->LDS, 16B per lane. LDS dest wave-uniform base; HW adds lane*16.
__device__ __forceinline__ void gload_lds16(const u16* g, u16* l) {
    __builtin_amdgcn_global_load_lds(
        (const __attribute__((address_space(1))) void*)g,
        (__attribute__((address_space(3))) void*)l,
        16, 0, 0);
}

#define BK 64

// ======= GEMM1 (conversion-fused): QK = f2bf(x) @ [wq|wk]^T + biasQK, bf16 + ssq =======
// A read as fp32 from x, converted in-register during staging (RNE, identical to old
// convert_x), ds_write'd into the SAME linear+XOR-swizzled LDS layout gload_lds produced.
// B staged via gload_lds. One-barrier-per-tile double buffer:
//   issue A-regs(t+1)+B-gloads(t+1) -> compute(t) -> cvt+ds_write A(t+1) -> syncthreads.
// Hazards: iter t+1 writes buf(t&1) only after end-of-t barrier (all reads done);
// buf((t+1)&1) sealed by the same barrier (vmcnt0+lgkmcnt0 drain at syncthreads).
__global__ __launch_bounds__(512, 1) void gemm1_kernel(
    const float* __restrict__ X,      // x fp32 [32768][512]
    const u16* __restrict__ Bt,       // Bt1 [1024][512]
    const float* __restrict__ bias,   // biasQK [1024]
    float* __restrict__ ssq_out,      // [2][32768]
    u16* __restrict__ C16)            // QK [32768][1024]
{
    __shared__ __attribute__((aligned(16))) u16 lds[2 * 32768];  // 128 KiB -> 1 block/CU
    const int tid  = threadIdx.x;
    const int wave = tid >> 6;
    const int lane = tid & 63;
    const int quad = lane >> 4;
    const int l16  = lane & 15;
    const int wm = wave >> 2, wn = wave & 3;

    const int gx   = gridDim.x;                 // 4
    const int nwg  = gx * gridDim.y;            // 512, %8==0
    const int wgid = blockIdx.y * gx + blockIdx.x;
    const int cpx  = nwg >> 3;
    const int swz  = (wgid & 7) * cpx + (wgid >> 3);
    const int row0 = (swz / gx) * 256;
    const int col0 = (swz % gx) * 256;

    floatx4 acc[8][4] = {};

    // chunk cc = wave*4+c covers 8 rows; lane l -> row cc*8+(l>>3), k-group (l&7)^rsub
    const int rsub = lane >> 3;
    const int s8   = ((lane & 7) ^ rsub) << 3;   // element offset of swizzled k-group
    const float* aptr[4]; const u16* bptr[4];
#pragma unroll
    for (int c = 0; c < 4; ++c) {
        const int cc = wave * 4 + c;
        aptr[c] = X  + (size_t)(row0 + cc * 8 + rsub) * 512 + s8;
        bptr[c] = Bt + (size_t)(col0 + cc * 8 + rsub) * 512 + s8;
    }
    const int NT = 8;
    float4 av[4][2];

#define LOADA(T)                                                              \
    _Pragma("unroll")                                                         \
    for (int c = 0; c < 4; ++c) {                                             \
        av[c][0] = *(const float4*)(aptr[c] + (T) * BK);                      \
        av[c][1] = *(const float4*)(aptr[c] + (T) * BK + 4);                  \
    }
#define LOADB(T, B)                                                           \
    _Pragma("unroll")                                                         \
    for (int c = 0; c < 4; ++c)                                               \
        gload_lds16(bptr[c] + (T) * BK, &lds[(B) * 32768 + 16384 + (wave * 4 + c) * 512]);
#define WRITEA(B)                                                             \
    _Pragma("unroll")                                                         \
    for (int c = 0; c < 4; ++c) {                                             \
        bf16x8 o;                                                             \
        union { u16 u; __bf16 b; } cv;                                        \
        cv.u = f2bf(av[c][0].x); o[0] = cv.b;                                 \
        cv.u = f2bf(av[c][0].y); o[1] = cv.b;                                 \
        cv.u = f2bf(av[c][0].z); o[2] = cv.b;                                 \
        cv.u = f2bf(av[c][0].w); o[3] = cv.b;                                 \
        cv.u = f2bf(av[c][1].x); o[4] = cv.b;                                 \
        cv.u = f2bf(av[c][1].y); o[5] = cv.b;                                 \
        cv.u = f2bf(av[c][1].z); o[6] = cv.b;                                 \
        cv.u = f2bf(av[c][1].w); o[7] = cv.b;                                 \
        *(bf16x8*)&lds[(B) * 32768 + (wave * 4 + c) * 512 + lane * 8] = o;    \
    }

    // prologue: stage tile 0 into buf 0
    LOADA(0);
    LOADB(0, 0);
    WRITEA(0);
    __syncthreads();

    for (int t = 0; t < NT; ++t) {
        if (t + 1 < NT) { LOADA(t + 1); LOADB(t + 1, (t + 1) & 1); }
        const u16* sA = &lds[(t & 1) * 32768];
        const u16* sB = sA + 16384;
#pragma unroll
        for (int ks = 0; ks < 2; ++ks) {
            const int pgo = (((ks * 4 + quad) ^ (l16 & 7)) << 3);
            bf16x8 bfr[4];
#pragma unroll
            for (int n = 0; n < 4; ++n)
                bfr[n] = *(const bf16x8*)&sB[(wn * 64 + n * 16 + l16) * 64 + pgo];
            __builtin_amdgcn_s_setprio(1);
#pragma unroll
            for (int m = 0; m < 8; ++m) {
                bf16x8 af = *(const bf16x8*)&sA[(wm * 128 + m * 16 + l16) * 64 + pgo];
#pragma unroll
                for (int n = 0; n < 4; ++n)
                    acc[m][n] = __builtin_amdgcn_mfma_f32_16x16x32_bf16(af, bfr[n], acc[m][n], 0, 0, 0);
            }
            __builtin_amdgcn_s_setprio(0);
        }
        if (t + 1 < NT) WRITEA((t + 1) & 1);
        __syncthreads();   // seals ds_writes (lgkm) + B gloads (vmcnt) for tile t+1
    }
#undef LOADA
#undef LOADB
#undef WRITEA

    // epilogue: bf16 repack + per-row output ssq (validated R5-R9)
    u16* til = lds;  // [128][264]
#pragma unroll
    for (int h = 0; h < 2; ++h) {
        __syncthreads();
        if (wm == h) {
            float bv[4];
#pragma unroll
            for (int n = 0; n < 4; ++n) bv[n] = bias[col0 + wn * 64 + n * 16 + l16];
#pragma unroll
            for (int m = 0; m < 8; ++m) {
                int rowl = m * 16 + quad * 4;
#pragma unroll
                for (int n = 0; n < 4; ++n) {
                    int tcol = wn * 64 + n * 16 + l16;
#pragma unroll
                    for (int t = 0; t < 4; ++t)
                        til[(rowl + t) * 264 + tcol] = f2bf(acc[m][n][t] + bv[n]);
                }
            }
        }
        __syncthreads();
        float ssl[8];
#pragma unroll
        for (int c = 0; c < 8; ++c) {
            int r  = c * 16 + (tid >> 5);
            int cu = (tid & 31) * 8;
            ushort4 lo = *(const ushort4*)&til[r * 264 + cu];
            ushort4 hi = *(const ushort4*)&til[r * 264 + cu + 4];
            u16x8 o;
            o[0] = lo.x; o[1] = lo.y; o[2] = lo.z; o[3] = lo.w;
            o[4] = hi.x; o[5] = hi.y; o[6] = hi.z; o[7] = hi.w;
            *(u16x8*)&C16[(size_t)(row0 + h * 128 + r) * 1024 + col0 + cu] = o;
            float ss = 0.f;
#pragma unroll
            for (int q2 = 0; q2 < 8; ++q2) { float f = bf2f(o[q2]); ss += f * f; }
            ssl[c] = ss;
        }
        float* so = ssq_out + (size_t)(col0 >> 9) * 32768 + row0 + h * 128;
#pragma unroll
        for (int c = 0; c < 8; ++c) {
            float s = ssl[c];
            s += __shfl_xor(s, 1);
            s += __shfl_xor(s, 2);
            s += __shfl_xor(s, 4);
            s += __shfl_xor(s, 8);
            s += __shfl_xor(s, 16);
            if ((lane & 31) == 0) atomicAdd(&so[c * 16 + (tid >> 5)], s);
        }
    }
}

// ====== fused GEMM23: out = rsq*(Q@wf) + rsk*(K@diag(g)(wp@wf)) + bpf, fp32 out =======
// Byte-identical body to R8/R9 (proven).
__global__ __launch_bounds__(512, 2) void gemm_qk_kernel(
    const u16* __restrict__ A,        // QK [32768][1024]
    const u16* __restrict__ BtF,      // [512][512] wf^T
    const u16* __restrict__ BtPF,     // [8][512][512] diag(g_b)*(wp@wf), n-major
    const float* __restrict__ bpf,    // [512] = bp@wf + bf
    const float* __restrict__ ssqQ,
    const float* __restrict__ ssqK,
    float* __restrict__ C32)          // out [32768][512]
{
    __shared__ __attribute__((aligned(16))) u16 lds[2 * 32768];  // 128 KiB
    const int tid  = threadIdx.x;
    const int wave = tid >> 6;
    const int lane = tid & 63;
    const int quad = lane >> 4;
    const int l16  = lane & 15;
    const int wm = wave >> 2, wn = wave & 3;

    const int gx   = gridDim.x;                 // 2
    const int nwg  = gx * gridDim.y;            // 256, %8==0
    const int wgid = blockIdx.y * gx + blockIdx.x;
    const int cpx  = nwg >> 3;
    const int swz  = (wgid & 7) * cpx + (wgid >> 3);
    const int row0 = (swz / gx) * 256;
    const int col0 = (swz % gx) * 256;
    const int batch = row0 >> 12;

    floatx4 acc[8][4] = {};

    const int rsub = lane >> 3;
    const int ksub = ((lane & 7) ^ rsub) << 3;
    const u16* aptr[4]; const u16* bptrF[4]; const u16* bptrP[4];
    const u16* BP = BtPF + (size_t)batch * 262144;
#pragma unroll
    for (int c = 0; c < 4; ++c) {
        const int cc = wave * 4 + c;
        aptr[c]  = A   + (size_t)(row0 + cc * 8 + rsub) * 1024 + ksub;
        bptrF[c] = BtF + (size_t)(col0 + cc * 8 + rsub) * 512  + ksub;
        bptrP[c] = BP  + (size_t)(col0 + cc * 8 + rsub) * 512  + ksub;
    }
    const int NT = 16;

#define STAGEQ(T, B)                                                          \
    {                                                                         \
        u16* dA_ = &lds[(B) * 32768];                                         \
        u16* dB_ = dA_ + 16384;                                               \
        const int kt_ = (T) * BK;                                             \
        _Pragma("unroll")                                                     \
        for (int c = 0; c < 4; ++c) {                                         \
            const int cc = wave * 4 + c;                                      \
            gload_lds16(aptr[c] + kt_, dA_ + cc * 512);                       \
            const u16* bsrc_ = (kt_ < 512) ? (bptrF[c] + kt_)                 \
                                           : (bptrP[c] + (kt_ - 512));        \
            gload_lds16(bsrc_, dB_ + cc * 512);                               \
        }                                                                     \
    }

    STAGEQ(0, 0);
    STAGEQ(1, 1);
    for (int t = 0; t < NT; ++t) {
        if (t + 1 < NT) asm volatile("s_waitcnt vmcnt(8)" ::: "memory");
        else            asm volatile("s_waitcnt vmcnt(0)" ::: "memory");
        __builtin_amdgcn_s_barrier();
        __builtin_amdgcn_sched_barrier(0);
        const u16* sA = &lds[(t & 1) * 32768];
        const u16* sB = sA + 16384;
#pragma unroll
        for (int ks = 0; ks < 2; ++ks) {
            const int pgo = (((ks * 4 + quad) ^ (l16 & 7)) << 3);
            bf16x8 bfr[4];
#pragma unroll
            for (int n = 0; n < 4; ++n)
                bfr[n] = *(const bf16x8*)&sB[(wn * 64 + n * 16 + l16) * 64 + pgo];
            __builtin_amdgcn_s_setprio(1);
#pragma unroll
            for (int m = 0; m < 8; ++m) {
                bf16x8 af = *(const bf16x8*)&sA[(wm * 128 + m * 16 + l16) * 64 + pgo];
#pragma unroll
                for (int n = 0; n < 4; ++n)
                    acc[m][n] = __builtin_amdgcn_mfma_f32_16x16x32_bf16(af, bfr[n], acc[m][n], 0, 0, 0);
            }
            __builtin_amdgcn_s_setprio(0);
        }
        // end of Q-half: acc holds Sq = Q@wf; rescale so final *rsk yields rsq*Sq + rsk*Sk
        if (t == 7) {
#pragma unroll
            for (int m = 0; m < 8; ++m) {
                int rowb = row0 + wm * 128 + m * 16 + quad * 4;
                float4 q4 = *(const float4*)&ssqQ[rowb];
                float4 k4 = *(const float4*)&ssqK[rowb];
                float ratio[4];
                ratio[0] = rsqrtf(fmaxf(q4.x, 1e-12f)) / rsqrtf(fmaxf(k4.x, 1e-12f));
                ratio[1] = rsqrtf(fmaxf(q4.y, 1e-12f)) / rsqrtf(fmaxf(k4.y, 1e-12f));
                ratio[2] = rsqrtf(fmaxf(q4.z, 1e-12f)) / rsqrtf(fmaxf(k4.z, 1e-12f));
                ratio[3] = rsqrtf(fmaxf(q4.w, 1e-12f)) / rsqrtf(fmaxf(k4.w, 1e-12f));
#pragma unroll
                for (int n = 0; n < 4; ++n)
#pragma unroll
                    for (int tt = 0; tt < 4; ++tt)
                        acc[m][n][tt] *= ratio[tt];
            }
        }
        __builtin_amdgcn_sched_barrier(0);
        asm volatile("" ::: "memory");
        __builtin_amdgcn_s_barrier();
        asm volatile("" ::: "memory");
        if (t + 2 < NT) STAGEQ(t + 2, t & 1);
    }
#undef STAGEQ

    // epilogue: fp32, out = acc*rsk + bpf; 4 passes of 64 rows through [64][264] f32 tile
    float* ftile = (float*)lds;
#pragma unroll
    for (int p = 0; p < 4; ++p) {
        __syncthreads();
        if (wm == (p >> 1)) {
            float bv[4];
#pragma unroll
            for (int n = 0; n < 4; ++n) bv[n] = bpf[col0 + wn * 64 + n * 16 + l16];
#pragma unroll
            for (int mi = 0; mi < 4; ++mi) {
                int m = (p & 1) * 4 + mi;
                int rowl = mi * 16 + quad * 4;
                int rowb = row0 + p * 64 + rowl;
                float4 k4 = *(const float4*)&ssqK[rowb];
                float rsk4[4];
                rsk4[0] = rsqrtf(fmaxf(k4.x, 1e-12f));
                rsk4[1] = rsqrtf(fmaxf(k4.y, 1e-12f));
                rsk4[2] = rsqrtf(fmaxf(k4.z, 1e-12f));
                rsk4[3] = rsqrtf(fmaxf(k4.w, 1e-12f));
#pragma unroll
                for (int n = 0; n < 4; ++n) {
                    int tcol = wn * 64 + n * 16 + l16;
#pragma unroll
                    for (int t = 0; t < 4; ++t)
                        ftile[(rowl + t) * 264 + tcol] = acc[m][n][t] * rsk4[t] + bv[n];
                }
            }
        }
        __syncthreads();
#pragma unroll
        for (int c = 0; c < 8; ++c) {
            int r  = c * 8 + wave;
            int cu = lane * 4;
            float4 v = *(const float4*)&ftile[r * 264 + cu];
            *(float4*)&C32[(size_t)(row0 + p * 64 + r) * 512 + col0 + cu] = v;
        }
    }
}

// ====== gsum_p: blocks [0,256) gsum; blocks [256,272) P^T GEMM (independent work) ======
__global__ __launch_bounds__(256) void gsum_p_kernel(
    const u16* __restrict__ QK, const float* __restrict__ ssqQ, float* __restrict__ g,
    const u16* __restrict__ BtF, const u16* __restrict__ wpb, u16* __restrict__ Pt)
{
    __shared__ __attribute__((aligned(16))) char shmem[128 * 132 * 2];  // 33792 B
    const int tid  = threadIdx.x;
    const int lane = tid & 63;
    const int wave = tid >> 6;

    if (blockIdx.x < 256) {
        float (*gtile)[512] = (float(*)[512])shmem;
        const int row0 = blockIdx.x * 128 + wave * 32;
        const int batch = row0 >> 12;
        const int d = lane * 8;
        float gacc[8] = {};
        for (int rr = 0; rr < 32; ++rr) {
            int row = row0 + rr;
            float s = rsqrtf(fmaxf(ssqQ[row], 1e-12f));
            u16x8 q = *(const u16x8*)(QK + (size_t)row * 1024 + d);
#pragma unroll
            for (int i = 0; i < 8; ++i) gacc[i] += s * bf2f(q[i]);
        }
#pragma unroll
        for (int i = 0; i < 8; ++i) gtile[wave][d + i] = gacc[i];
        __syncthreads();
        int c2 = tid * 2;
        float s0 = gtile[0][c2]     + gtile[1][c2]     + gtile[2][c2]     + gtile[3][c2];
        float s1 = gtile[0][c2 + 1] + gtile[1][c2 + 1] + gtile[2][c2 + 1] + gtile[3][c2 + 1];
        atomicAdd(&g[batch * 512 + c2], s0);
        atomicAdd(&g[batch * 512 + c2 + 1], s1);
        return;
    }

    // P role: 16 blocks, 128x128 tiles of Pt = (wp@wf)^T
    u16* lds  = (u16*)shmem;
    u16* lsA  = lds;
    u16* lsB  = lds + 128 * BK;
    const int quad = lane >> 4;
    const int l16  = lane & 15;
    const int wm = wave >> 1, wn = wave & 1;
    const int bid2 = blockIdx.x - 256;
    const int row0 = (bid2 >> 2) * 128;
    const int col0 = (bid2 & 3) * 128;

    floatx4 acc[4][4] = {};
    const int rsub = lane >> 3;
    const int ksub = ((lane & 7) ^ rsub) << 3;
    const u16* aptr[4]; const u16* bptr[4];
#pragma unroll
    for (int c = 0; c < 4; ++c) {
        const int cc = wave * 4 + c;
        aptr[c] = BtF + (size_t)(row0 + cc * 8 + rsub) * 512 + ksub;
        bptr[c] = wpb + (size_t)(col0 + cc * 8 + rsub) * 512 + ksub;
    }
    for (int kt = 0; kt < 512; kt += BK) {
#pragma unroll
        for (int c = 0; c < 4; ++c) {
            const int cc = wave * 4 + c;
            gload_lds16(aptr[c] + kt, &lsA[cc * 512]);
            gload_lds16(bptr[c] + kt, &lsB[cc * 512]);
        }
        __syncthreads();
#pragma unroll
        for (int ks = 0; ks < 2; ++ks) {
            const int pgo = (((ks * 4 + quad) ^ (l16 & 7)) << 3);
            bf16x8 af[4], bfr[4];
#pragma unroll
            for (int i = 0; i < 4; ++i)
                af[i] = *(const bf16x8*)&lsA[(wm * 64 + i * 16 + l16) * BK + pgo];
#pragma unroll
            for (int j = 0; j < 4; ++j)
                bfr[j] = *(const bf16x8*)&lsB[(wn * 64 + j * 16 + l16) * BK + pgo];
#pragma unroll
            for (int i = 0; i < 4; ++i)
#pragma unroll
                for (int j = 0; j < 4; ++j)
                    acc[i][j] = __builtin_amdgcn_mfma_f32_16x16x32_bf16(af[i], bfr[j], acc[i][j], 0, 0, 0);
        }
        __syncthreads();
    }
#pragma unroll
    for (int j = 0; j < 4; ++j) {
        int tcol = wn * 64 + j * 16 + l16;
#pragma unroll
        for (int i = 0; i < 4; ++i) {
            int trow = wm * 64 + i * 16 + quad * 4;
#pragma unroll
            for (int t = 0; t < 4; ++t)
                lds[(trow + t) * 132 + tcol] = f2bf(acc[i][j][t]);
        }
    }
    __syncthreads();
#pragma unroll
    for (int c = 0; c < 8; ++c) {
        int r  = c * 16 + (tid >> 4);
        int cu = (tid & 15) * 8;
        ushort4 lo = *(const ushort4*)&lds[r * 132 + cu];
        ushort4 hi = *(const ushort4*)&lds[r * 132 + cu + 4];
        u16x8 o;
        o[0] = lo.x; o[1] = lo.y; o[2] = lo.z; o[3] = lo.w;
        o[4] = hi.x; o[5] = hi.y; o[6] = hi.z; o[7] = hi.w;
        *(u16x8*)&Pt[(size_t)(row0 + r) * 512 + col0 + cu] = o;
    }
}

// BtPF[b][n][kk] = g_b[kk] * Pt[n][kk]   (8x512x512, vectorized 8-wide)
__global__ __launch_bounds__(256) void scalePF_kernel(const u16* __restrict__ Pt,
                                                      const float* __restrict__ g,
                                                      u16* __restrict__ BtPF)
{
    size_t i8 = ((size_t)blockIdx.x * 256 + threadIdx.x) * 8;  // over 2,097,152
    int b   = (int)(i8 >> 18);
    int rem = (int)(i8 & 262143);
    int kk  = rem & 511;
    u16x8 p = *(const u16x8*)(Pt + rem);
    float4 g0 = *(const float4*)(g + b * 512 + kk);
    float4 g1 = *(const float4*)(g + b * 512 + kk + 4);
    u16x8 o;
    o[0] = f2bf(bf2f(p[0]) * g0.x); o[1] = f2bf(bf2f(p[1]) * g0.y);
    o[2] = f2bf(bf2f(p[2]) * g0.z); o[3] = f2bf(bf2f(p[3]) * g0.w);
    o[4] = f2bf(bf2f(p[4]) * g1.x); o[5] = f2bf(bf2f(p[5]) * g1.y);
    o[6] = f2bf(bf2f(p[6]) * g1.z); o[7] = f2bf(bf2f(p[7]) * g1.w);
    *(u16x8*)(BtPF + (size_t)b * 262144 + rem) = o;
}

// ====== prep_w: weights only — transpose3 + convert_wp + biasQK + bpf (1044 blocks) ====
// roles: [0,768) transpose3; [768,1024) convert_wp; [1024,1028) biasQK; [1028,1044) bpf.
// bpf zero-initialized by the preceding hipMemsetAsync.
__global__ __launch_bounds__(256) void prep_w_kernel(
    const float* __restrict__ wq, const float* __restrict__ wk, const float* __restrict__ wf,
    u16* __restrict__ Bt1, u16* __restrict__ BtF,
    const float* __restrict__ wp, u16* __restrict__ wpb,
    const float* __restrict__ bq, const float* __restrict__ bk, float* __restrict__ biasQK,
    const float* __restrict__ bp, const float* __restrict__ bfv, float* __restrict__ bpf)
{
    __shared__ u16 tile[32][34];
    const int bid = blockIdx.x;
    const int tid = threadIdx.x;

    if (bid < 768) {                         // transpose3: wq,wk,wf -> B^T bf16
        const int which = bid >> 8;
        const float* W = (which == 0) ? wq : (which == 1) ? wk : wf;
        u16* Bt = (which == 0) ? Bt1 : (which == 1) ? (Bt1 + 512 * 512) : BtF;
        const int b2 = bid & 255;
        const int tk = b2 & 15;
        const int tn = b2 >> 4;
        const int c  = tid & 31;
        const int r0 = tid >> 5;
#pragma unroll
        for (int i = 0; i < 4; ++i) {
            int r = r0 + i * 8;
            tile[r][c] = f2bf(W[(size_t)(tk * 32 + r) * 512 + tn * 32 + c]);
        }
        __syncthreads();
#pragma unroll
        for (int i = 0; i < 4; ++i) {
            int r = r0 + i * 8;
            Bt[(size_t)(tn * 32 + r) * 512 + tk * 32 + c] = tile[c][r];
        }
    } else if (bid < 1024) {                 // convert_wp: fp32 -> bf16 row-major
        size_t i = ((size_t)(bid - 768) * 256 + tid) * 4;
        float4 v = *(const float4*)(wp + i);
        ushort4 o;
        o.x = f2bf(v.x); o.y = f2bf(v.y); o.z = f2bf(v.z); o.w = f2bf(v.w);
        *(ushort4*)(wpb + i) = o;
    } else if (bid < 1028) {                 // biasQK = [bq|bk]
        int id = (bid - 1024) * 256 + tid;   // 0..1023
        biasQK[id] = (id < 512) ? bq[id] : bk[id - 512];
    } else {                                 // bpf += partial(bp@wf) [+ bf]
        const int bb = bid - 1028;           // 0..15
        const int j0 = bb * 32;
        float s0 = 0.f, s1 = 0.f;
#pragma unroll 4
        for (int j = j0; j < j0 + 32; ++j) {
            s0 += bp[j] * wf[(size_t)j * 512 + tid];
            s1 += bp[j] * wf[(size_t)j * 512 + tid + 256];
        }
        if (bb == 0) { s0 += bfv[tid]; s1 += bfv[tid + 256]; }
        atomicAdd(&bpf[tid], s0);
        atomicAdd(&bpf[tid + 256], s1);
    }
}

extern "C" void kernel_launch(void* const* d_in, const int* in_sizes, int n_in,
                              void* d_out, int out_size, void* d_ws, size_t ws_size,
                              hipStream_t stream)
{
    const float* x  = (const float*)d_in[0];
    const float* wq = (const float*)d_in[1];
    const float* bq = (const float*)d_in[2];
    const float* wk = (const float*)d_in[3];
    const float* bk = (const float*)d_in[4];
    const float* wp = (const float*)d_in[5];
    const float* bp = (const float*)d_in[6];
    const float* wf = (const float*)d_in[7];
    const float* bf = (const float*)d_in[8];
    // d_in[9] = w_g unused: softmax over a size-1 axis is identically 1.

    char* ws = (char*)d_ws;
    u16*   QK     = (u16*)(ws + 33554432);      // 32768x1024 bf16 = 64 MiB
    u16*   Bt1    = (u16*)(ws + 100663296);     // 1024x512
    u16*   BtF    = (u16*)(ws + 101711872);     // 512x512 (wf^T)
    u16*   wpb    = (u16*)(ws + 102236160);     // 512x512 (wp bf16, row-major)
    u16*   Pt     = (u16*)(ws + 102760448);     // 512x512 ((wp@wf)^T, n-major)
    u16*   BtPF   = (u16*)(ws + 103284736);     // 8x512x512 = 4 MiB
    float* biasQK = (float*)(ws + 107479040);   // 1024
    float* g      = (float*)(ws + 107483136);   // 8x512        (16 KiB)
    float* ssq    = (float*)(ws + 107499520);   // 2x32768      (256 KiB, contiguous after g)
    float* bpf    = (float*)(ws + 107761664);   // 512          (contiguous after ssq)

    // one memset covers g | ssq | bpf (contiguous): 16384 + 262144 + 2048 B
    hipMemsetAsync(g, 0, 280576, stream);
    // prep_w: transpose3 + convert_wp + biasQK + bpf  (weights only, ~3 MB traffic)
    prep_w_kernel<<<1044, 256, 0, stream>>>(wq, wk, wf, Bt1, BtF, wp, wpb,
                                            bq, bk, biasQK, bp, bf, bpf);
    // QK = f2bf(x) @ [wq|wk] + [bq|bk]  (conversion fused into A-staging)   nwg = 512
    gemm1_kernel<<<dim3(4, 128), 512, 0, stream>>>(x, Bt1, biasQK, ssq, QK);
    // gsum (g) + Pt = (wp@wf)^T  (independent P rides along)                272 blocks
    gsum_p_kernel<<<272, 256, 0, stream>>>(QK, ssq, g, BtF, wpb, Pt);
    // BtPF[b] = diag-scale of Pt by g_b
    scalePF_kernel<<<1024, 256, 0, stream>>>(Pt, g, BtPF);
    // out = rsq*(Q@wf) + rsk*(K@diag(g)(wp@wf)) + bp@wf + bf   (fp32)       nwg = 256
    gemm_qk_kernel<<<dim3(2, 128), 512, 0, stream>>>(QK, BtF, BtPF, bpf, ssq, ssq + 32768, (float*)d_out);
}